// Round 1
// baseline (678.988 us; speedup 1.0000x reference)
//
#include <hip/hip_runtime.h>
#include <stdint.h>

#define Bn 16
#define Sn 256
#define Vn 21128
#define NV4 5282      // Vn/4 exactly
#define RANKn 32
#define BEAMn 64
#define HBINS 4096
#define CAPn 512
#define LOG2E 1.44269504088896340736f
#define LN2   0.69314718055994530942f

// v_exp_f32 / v_log_f32 are base-2:
#define EXP2F(x) __builtin_amdgcn_exp2f(x)
#define LOG2F(x) __builtin_amdgcn_logf(x)

__device__ __forceinline__ unsigned f2o(unsigned b) {  // float bits -> order-preserving uint
    return (b & 0x80000000u) ? ~b : (b | 0x80000000u);
}
__device__ __forceinline__ float o2f(unsigned u) {
    unsigned b = (u & 0x80000000u) ? (u ^ 0x80000000u) : ~u;
    return __uint_as_float(b);
}
__device__ __forceinline__ float rdlane(float v, int lane) {
    return __int_as_float(__builtin_amdgcn_readlane(__float_as_int(v), lane));
}

// One block per (b,s) row: radix-select top-64, force-include target.
__global__ __launch_bounds__(256) void topk_kernel(const float* __restrict__ emis,
                                                   const int* __restrict__ targets,
                                                   int* __restrict__ beam_idx,
                                                   float* __restrict__ beam_val) {
    const int row = blockIdx.x;            // b*Sn + s
    const float* __restrict__ rowp = emis + (size_t)row * Vn;
    const int tgt = targets[row];
    __shared__ unsigned hist[HBINS];
    __shared__ unsigned csum[256];
    __shared__ unsigned cu[CAPn];
    __shared__ int      cix[CAPn];
    __shared__ int      selidx[BEAMn];
    __shared__ float    selval[BEAMn];
    __shared__ unsigned ccount;
    __shared__ int      binstar;
    __shared__ int      chunkc;
    __shared__ int      hastgt;
    const int t = threadIdx.x;
    for (int i = t; i < HBINS; i += 256) hist[i] = 0;
    if (t == 0) { ccount = 0; hastgt = 0; }
    __syncthreads();
    uint4 vals[21];
    #pragma unroll
    for (int it = 0; it < 21; ++it) {
        int v4 = t + it * 256;
        if (v4 < NV4) {
            const uint4 raw = ((const uint4*)rowp)[v4];
            uint4 u;
            u.x = f2o(raw.x); u.y = f2o(raw.y); u.z = f2o(raw.z); u.w = f2o(raw.w);
            vals[it] = u;
            atomicAdd(&hist[u.x >> 20], 1u);
            atomicAdd(&hist[u.y >> 20], 1u);
            atomicAdd(&hist[u.z >> 20], 1u);
            atomicAdd(&hist[u.w >> 20], 1u);
        }
    }
    __syncthreads();
    unsigned cs = 0;
    #pragma unroll
    for (int i = 0; i < 16; ++i) cs += hist[t * 16 + i];
    csum[t] = cs;
    __syncthreads();
    for (int off = 1; off < 256; off <<= 1) {
        unsigned v = csum[t] + ((t + off < 256) ? csum[t + off] : 0u);
        __syncthreads();
        csum[t] = v;
        __syncthreads();
    }
    if (csum[t] >= BEAMn && (t == 255 || csum[t + 1] < BEAMn)) chunkc = t;
    __syncthreads();
    if (t == 0) {
        int tc = chunkc;
        unsigned acc = (tc == 255) ? 0u : csum[tc + 1];
        int bs = tc * 16;
        for (int b2 = tc * 16 + 15; b2 >= tc * 16; --b2) {
            acc += hist[b2];
            if (acc >= BEAMn) { bs = b2; break; }
        }
        binstar = bs;
    }
    __syncthreads();
    const unsigned bstar = (unsigned)binstar;
    #pragma unroll
    for (int it = 0; it < 21; ++it) {
        int v4 = t + it * 256;
        if (v4 < NV4) {
            uint4 u = vals[it];
            int bi = v4 * 4;
            if ((u.x >> 20) >= bstar) { unsigned p = atomicAdd(&ccount, 1u); if (p < CAPn) { cu[p] = u.x; cix[p] = bi;     } }
            if ((u.y >> 20) >= bstar) { unsigned p = atomicAdd(&ccount, 1u); if (p < CAPn) { cu[p] = u.y; cix[p] = bi + 1; } }
            if ((u.z >> 20) >= bstar) { unsigned p = atomicAdd(&ccount, 1u); if (p < CAPn) { cu[p] = u.z; cix[p] = bi + 2; } }
            if ((u.w >> 20) >= bstar) { unsigned p = atomicAdd(&ccount, 1u); if (p < CAPn) { cu[p] = u.w; cix[p] = bi + 3; } }
        }
    }
    __syncthreads();
    const int C = (int)min(ccount, (unsigned)CAPn);
    for (int p = t; p < C; p += 256) {
        unsigned up = cu[p]; int ip = cix[p];
        int rank = 0;
        for (int q = 0; q < C; ++q) {
            unsigned uq = cu[q];
            rank += (uq > up) || (uq == up && cix[q] < ip);
        }
        if (rank < BEAMn) { selidx[rank] = ip; selval[rank] = o2f(up); }
    }
    __syncthreads();
    if (t < BEAMn && selidx[t] == tgt) hastgt = 1;
    __syncthreads();
    if (t == 0 && !hastgt) { selidx[BEAMn - 1] = tgt; selval[BEAMn - 1] = rowp[tgt]; }
    __syncthreads();
    if (t < BEAMn) {
        beam_idx[(size_t)row * BEAMn + t] = selidx[t];
        beam_val[(size_t)row * BEAMn + t] = selval[t];
    }
}

// transM[b,k,i,j] = exp2( dot32(E1[beam[b,k,i]], E2[beam[b,k+1,j]]) * LOG2E )
// LINEAR domain (values ~[0.9,1.1]); consumed only by scan_kernel.
#define TPAD 68
__global__ __launch_bounds__(256) void trans_kernel(const float* __restrict__ E1,
                                                    const float* __restrict__ E2,
                                                    const int* __restrict__ beam_idx,
                                                    float* __restrict__ trans) {
    const int blk = blockIdx.x;           // b*(Sn-1) + k
    const int b = blk / (Sn - 1);
    const int k = blk - b * (Sn - 1);
    const int* bi = beam_idx + ((size_t)(b * Sn + k)) * BEAMn;
    const int* bj = beam_idx + ((size_t)(b * Sn + k + 1)) * BEAMn;
    __shared__ float e1t[RANKn][TPAD];
    __shared__ float e2t[RANKn][TPAD];
    const int t = threadIdx.x;
    {
        const int row = t >> 2, q = t & 3;
        const int rb = q * 8;
        int i1 = bi[row];
        const float4* s1 = (const float4*)(E1 + (size_t)i1 * RANKn) + q * 2;
        float4 a0 = s1[0], a1 = s1[1];
        e1t[rb + 0][row] = a0.x; e1t[rb + 1][row] = a0.y; e1t[rb + 2][row] = a0.z; e1t[rb + 3][row] = a0.w;
        e1t[rb + 4][row] = a1.x; e1t[rb + 5][row] = a1.y; e1t[rb + 6][row] = a1.z; e1t[rb + 7][row] = a1.w;
        int i2 = bj[row];
        const float4* s2 = (const float4*)(E2 + (size_t)i2 * RANKn) + q * 2;
        float4 b0 = s2[0], b1 = s2[1];
        e2t[rb + 0][row] = b0.x; e2t[rb + 1][row] = b0.y; e2t[rb + 2][row] = b0.z; e2t[rb + 3][row] = b0.w;
        e2t[rb + 4][row] = b1.x; e2t[rb + 5][row] = b1.y; e2t[rb + 6][row] = b1.z; e2t[rb + 7][row] = b1.w;
    }
    __syncthreads();
    const int ti = t & 15, tj = t >> 4;
    const int i0 = ti * 4, j0 = tj * 4;
    float acc[4][4] = {};
    #pragma unroll
    for (int r = 0; r < RANKn; ++r) {
        float4 a = *(const float4*)&e1t[r][i0];
        float4 bb = *(const float4*)&e2t[r][j0];
        acc[0][0] += a.x * bb.x; acc[0][1] += a.x * bb.y; acc[0][2] += a.x * bb.z; acc[0][3] += a.x * bb.w;
        acc[1][0] += a.y * bb.x; acc[1][1] += a.y * bb.y; acc[1][2] += a.y * bb.z; acc[1][3] += a.y * bb.w;
        acc[2][0] += a.z * bb.x; acc[2][1] += a.z * bb.y; acc[2][2] += a.z * bb.z; acc[2][3] += a.z * bb.w;
        acc[3][0] += a.w * bb.x; acc[3][1] += a.w * bb.y; acc[3][2] += a.w * bb.z; acc[3][3] += a.w * bb.w;
    }
    float* outp = trans + (size_t)blk * (BEAMn * BEAMn);
    #pragma unroll
    for (int ii = 0; ii < 4; ++ii) {
        float4 o = { EXP2F(acc[ii][0] * LOG2E), EXP2F(acc[ii][1] * LOG2E),
                     EXP2F(acc[ii][2] * LOG2E), EXP2F(acc[ii][3] * LOG2E) };
        *(float4*)&outp[(i0 + ii) * BEAMn + j0] = o;
    }
}

// Sequential scan, base-2 log scores + LINEAR transition matrix.
// One block (512 thr) per batch. All waves redundantly hold score[j] in lane j.
// Per step/lane: 1 exp2 (p_j), 8 readlane*fmac partials, 1 log2.
// Barrier is raw `s_waitcnt lgkmcnt(0); s_barrier` — does NOT drain vmcnt, so
// the named-register trans prefetch (depth 2 via unroll-3) stays in flight
// across steps (the __syncthreads vmcnt(0) drain was the 680ns/step stall).
// Mask row is pre-packed into 4x64-bit ballots at entry, so the per-step mask
// test is pure SALU/VALU — no scalar load left inside the lgkmcnt(0) shadow.
__global__ __launch_bounds__(512) void scan_kernel(const float* __restrict__ trans,
                                                   const float* __restrict__ beam_val,
                                                   const int* __restrict__ mask,
                                                   float* __restrict__ out) {
    const int b = blockIdx.x;
    const int t = threadIdx.x;
    const int c = t >> 6, j = t & 63;     // c: 8-row chunk of i; j = column = lane
    const float* __restrict__ trb = trans + (size_t)b * (Sn - 1) * (BEAMn * BEAMn);
    const float* __restrict__ bv  = beam_val + (size_t)b * Sn * BEAMn;
    const int* __restrict__ mk = mask + (size_t)b * Sn;
    __shared__ float psum[2][8][BEAMn + 1];

    // Pack mask row (256 ints) into 4 ballot words; identical in every wave.
    const unsigned long long mb0 = __ballot(mk[j] != 0);
    const unsigned long long mb1 = __ballot(mk[64 + j] != 0);
    const unsigned long long mb2 = __ballot(mk[128 + j] != 0);
    const unsigned long long mb3 = __ballot(mk[192 + j] != 0);

    float score_reg = bv[j] * LOG2E;      // identical in every wave
    float tba[8], tbb[8], tbc[8];
    float eba, ebb, ebc;
    const float* tp0 = trb + (c * 8) * BEAMn + j;
    #pragma unroll
    for (int r = 0; r < 8; ++r) tba[r] = tp0[r * BEAMn];           // tile 0
    #pragma unroll
    for (int r = 0; r < 8; ++r) tbb[r] = tp0[4096 + r * BEAMn];    // tile 1
    eba = bv[BEAMn + j] * LOG2E;
    ebb = bv[2 * BEAMn + j] * LOG2E;
    ebc = 0.f;

#define SSTEP(K, TA, EA, TC, EC)  {                                           \
    if ((K) + 2 < Sn - 1) {                                                   \
        const float* tpn = tp0 + (size_t)((K) + 2) * 4096;                    \
        _Pragma("unroll")                                                     \
        for (int r = 0; r < 8; ++r) TC[r] = tpn[r * BEAMn];                   \
        EC = bv[(size_t)((K) + 3) * BEAMn + j] * LOG2E;                       \
    }                                                                         \
    const float mt = rdlane(score_reg, 0);                                    \
    const float pj = EXP2F(score_reg - mt);                                   \
    float acc;                                                                \
    acc  = rdlane(pj, c * 8 + 0) * TA[0];                                     \
    acc += rdlane(pj, c * 8 + 1) * TA[1];                                     \
    acc += rdlane(pj, c * 8 + 2) * TA[2];                                     \
    acc += rdlane(pj, c * 8 + 3) * TA[3];                                     \
    acc += rdlane(pj, c * 8 + 4) * TA[4];                                     \
    acc += rdlane(pj, c * 8 + 5) * TA[5];                                     \
    acc += rdlane(pj, c * 8 + 6) * TA[6];                                     \
    acc += rdlane(pj, c * 8 + 7) * TA[7];                                     \
    psum[(K) & 1][c][j] = acc;                                                \
    __asm__ volatile("s_waitcnt lgkmcnt(0)\n\ts_barrier" ::: "memory");       \
    {                                                                         \
        const float (*ps)[BEAMn + 1] = psum[(K) & 1];                         \
        float tot = ps[0][j] + ps[1][j] + ps[2][j] + ps[3][j]                 \
                  + ps[4][j] + ps[5][j] + ps[6][j] + ps[7][j];                \
        float nxt = mt + LOG2F(tot) + EA;                                     \
        const int kk1 = (K) + 1;                                              \
        const unsigned long long bsel =                                       \
            (kk1 < 64) ? mb0 : (kk1 < 128) ? mb1 : (kk1 < 192) ? mb2 : mb3;  \
        score_reg = ((bsel >> (kk1 & 63)) & 1ull) ? nxt : score_reg;          \
    }                                                                         \
}

    for (int kb = 0; kb < Sn - 1; kb += 3) {       // 255 = 3*85
        SSTEP(kb,     tba, eba, tbc, ebc);
        SSTEP(kb + 1, tbb, ebb, tba, eba);
        SSTEP(kb + 2, tbc, ebc, tbb, ebb);
    }
#undef SSTEP

    if (t < BEAMn) {
        float v = score_reg;
        for (int off = 32; off; off >>= 1) v = fmaxf(v, __shfl_xor(v, off, 64));
        float e = EXP2F(score_reg - v);
        for (int off = 32; off; off >>= 1) e += __shfl_xor(e, off, 64);
        if (t == 0) atomicAdd(out, -LN2 * (v + LOG2F(e)));
    }
}

// numerator: sum over (b,s) of mask*(em + (s>0)*dot32(E1[tgt_prev],E2[tgt]))
__global__ __launch_bounds__(256) void num_kernel(const float* __restrict__ emis,
                                                  const int* __restrict__ targets,
                                                  const int* __restrict__ mask,
                                                  const float* __restrict__ E1,
                                                  const float* __restrict__ E2,
                                                  float* __restrict__ out) {
    const int gid = blockIdx.x * 256 + threadIdx.x;
    float val = 0.f;
    if (gid < Bn * Sn) {
        int s = gid & (Sn - 1);
        int tg = targets[gid];
        float em = emis[(size_t)gid * Vn + tg];
        float tr = 0.f;
        if (s > 0) {
            int pv = targets[gid - 1];
            const float4* p1 = (const float4*)(E1 + (size_t)pv * RANKn);
            const float4* p2 = (const float4*)(E2 + (size_t)tg * RANKn);
            #pragma unroll
            for (int r = 0; r < 8; ++r) {
                float4 a = p1[r], bb = p2[r];
                tr += a.x * bb.x + a.y * bb.y + a.z * bb.z + a.w * bb.w;
            }
        }
        if (mask[gid]) val = em + tr;
    }
    for (int off = 32; off; off >>= 1) val += __shfl_xor(val, off, 64);
    __shared__ float wsum[4];
    if ((threadIdx.x & 63) == 0) wsum[threadIdx.x >> 6] = val;
    __syncthreads();
    if (threadIdx.x == 0) atomicAdd(out, wsum[0] + wsum[1] + wsum[2] + wsum[3]);
}

extern "C" void kernel_launch(void* const* d_in, const int* in_sizes, int n_in,
                              void* d_out, int out_size, void* d_ws, size_t ws_size,
                              hipStream_t stream) {
    const float* emis    = (const float*)d_in[0];
    const int*   targets = (const int*)d_in[1];
    const int*   mask    = (const int*)d_in[2];   // bool input delivered as int32
    const float* E1      = (const float*)d_in[3];
    const float* E2      = (const float*)d_in[4];
    float* out = (float*)d_out;
    char* ws = (char*)d_ws;
    int*   beam_idx = (int*)ws;                          // 1 MB
    float* beam_val = (float*)(ws + (1 << 20));          // 1 MB
    float* trans    = (float*)(ws + (2 << 20));          // 16*255*4096*4 = 66.8 MB

    (void)hipMemsetAsync(out, 0, sizeof(float), stream);
    hipLaunchKernelGGL(topk_kernel, dim3(Bn * Sn), dim3(256), 0, stream,
                       emis, targets, beam_idx, beam_val);
    hipLaunchKernelGGL(trans_kernel, dim3(Bn * (Sn - 1)), dim3(256), 0, stream,
                       E1, E2, beam_idx, trans);
    hipLaunchKernelGGL(num_kernel, dim3((Bn * Sn + 255) / 256), dim3(256), 0, stream,
                       emis, targets, mask, E1, E2, out);
    hipLaunchKernelGGL(scan_kernel, dim3(Bn), dim3(512), 0, stream,
                       trans, beam_val, mask, out);
}

// Round 2
// 573.501 us; speedup vs baseline: 1.1839x; 1.1839x over previous
//
#include <hip/hip_runtime.h>
#include <stdint.h>

#define Bn 16
#define Sn 256
#define Vn 21128
#define NV4 5282      // Vn/4 exactly
#define RANKn 32
#define BEAMn 64
#define HBINS 4096
#define CAPn 512
#define NSEG 16
#define LOG2E 1.44269504088896340736f
#define LN2   0.69314718055994530942f

// v_exp_f32 / v_log_f32 are base-2:
#define EXP2F(x) __builtin_amdgcn_exp2f(x)
#define LOG2F(x) __builtin_amdgcn_logf(x)

__device__ __forceinline__ unsigned f2o(unsigned b) {  // float bits -> order-preserving uint
    return (b & 0x80000000u) ? ~b : (b | 0x80000000u);
}
__device__ __forceinline__ float o2f(unsigned u) {
    unsigned b = (u & 0x80000000u) ? (u ^ 0x80000000u) : ~u;
    return __uint_as_float(b);
}
__device__ __forceinline__ float dot4(float4 a, float4 b) {
    return a.x * b.x + a.y * b.y + a.z * b.z + a.w * b.w;
}

// One block per (b,s) row: exact top-64, force-include target.
// Fast path: fixed threshold THR=2.5 collects ~131 candidates for N(0,1) rows
// (no histogram, no LDS atomics on hot bins). Exact fallback (full radix
// histogram) when the candidate count falls outside [64, CAPn].
__global__ __launch_bounds__(256) void topk_kernel(const float* __restrict__ emis,
                                                   const int* __restrict__ targets,
                                                   int* __restrict__ beam_idx,
                                                   float* __restrict__ beam_val) {
    const int row = blockIdx.x;            // b*Sn + s
    const float* __restrict__ rowp = emis + (size_t)row * Vn;
    const int tgt = targets[row];
    __shared__ unsigned hist[HBINS];       // fallback only
    __shared__ unsigned csum[256];         // fallback only
    __shared__ unsigned cu[CAPn];
    __shared__ int      cix[CAPn];
    __shared__ int      selidx[BEAMn];
    __shared__ float    selval[BEAMn];
    __shared__ unsigned ccount;
    __shared__ int      binstar;
    __shared__ int      chunkc;
    __shared__ int      hastgt;
    __shared__ unsigned wcnt[4];
    const int t = threadIdx.x;
    if (t == 0) { ccount = 0; hastgt = 0; }

    const unsigned THRU = f2o(__float_as_uint(2.5f));   // order-domain threshold
    uint4 vals[21];
    unsigned cntl = 0;
    #pragma unroll
    for (int it = 0; it < 21; ++it) {
        int v4 = t + it * 256;
        if (v4 < NV4) {
            const uint4 raw = ((const uint4*)rowp)[v4];
            uint4 u;
            u.x = f2o(raw.x); u.y = f2o(raw.y); u.z = f2o(raw.z); u.w = f2o(raw.w);
            vals[it] = u;
            cntl += (u.x > THRU) + (u.y > THRU) + (u.z > THRU) + (u.w > THRU);
        }
    }
    for (int off = 32; off; off >>= 1) cntl += __shfl_xor(cntl, off, 64);
    if ((t & 63) == 0) wcnt[t >> 6] = cntl;
    __syncthreads();
    const unsigned C0 = wcnt[0] + wcnt[1] + wcnt[2] + wcnt[3];

    if (C0 >= BEAMn && C0 <= CAPn) {
        // ---- fast path: compact everything above THR (contains exact top-64)
        #pragma unroll
        for (int it = 0; it < 21; ++it) {
            int v4 = t + it * 256;
            if (v4 < NV4) {
                uint4 u = vals[it];
                int bi = v4 * 4;
                if (u.x > THRU) { unsigned p = atomicAdd(&ccount, 1u); cu[p] = u.x; cix[p] = bi;     }
                if (u.y > THRU) { unsigned p = atomicAdd(&ccount, 1u); cu[p] = u.y; cix[p] = bi + 1; }
                if (u.z > THRU) { unsigned p = atomicAdd(&ccount, 1u); cu[p] = u.z; cix[p] = bi + 2; }
                if (u.w > THRU) { unsigned p = atomicAdd(&ccount, 1u); cu[p] = u.w; cix[p] = bi + 3; }
            }
        }
    } else {
        // ---- exact fallback: 12-bit radix histogram select (original path)
        for (int i = t; i < HBINS; i += 256) hist[i] = 0;
        __syncthreads();
        #pragma unroll
        for (int it = 0; it < 21; ++it) {
            int v4 = t + it * 256;
            if (v4 < NV4) {
                uint4 u = vals[it];
                atomicAdd(&hist[u.x >> 20], 1u);
                atomicAdd(&hist[u.y >> 20], 1u);
                atomicAdd(&hist[u.z >> 20], 1u);
                atomicAdd(&hist[u.w >> 20], 1u);
            }
        }
        __syncthreads();
        unsigned cs = 0;
        #pragma unroll
        for (int i = 0; i < 16; ++i) cs += hist[t * 16 + i];
        csum[t] = cs;
        __syncthreads();
        for (int off = 1; off < 256; off <<= 1) {
            unsigned v = csum[t] + ((t + off < 256) ? csum[t + off] : 0u);
            __syncthreads();
            csum[t] = v;
            __syncthreads();
        }
        if (csum[t] >= BEAMn && (t == 255 || csum[t + 1] < BEAMn)) chunkc = t;
        __syncthreads();
        if (t == 0) {
            int tc = chunkc;
            unsigned acc = (tc == 255) ? 0u : csum[tc + 1];
            int bs = tc * 16;
            for (int b2 = tc * 16 + 15; b2 >= tc * 16; --b2) {
                acc += hist[b2];
                if (acc >= BEAMn) { bs = b2; break; }
            }
            binstar = bs;
        }
        __syncthreads();
        const unsigned bstar = (unsigned)binstar;
        #pragma unroll
        for (int it = 0; it < 21; ++it) {
            int v4 = t + it * 256;
            if (v4 < NV4) {
                uint4 u = vals[it];
                int bi = v4 * 4;
                if ((u.x >> 20) >= bstar) { unsigned p = atomicAdd(&ccount, 1u); if (p < CAPn) { cu[p] = u.x; cix[p] = bi;     } }
                if ((u.y >> 20) >= bstar) { unsigned p = atomicAdd(&ccount, 1u); if (p < CAPn) { cu[p] = u.y; cix[p] = bi + 1; } }
                if ((u.z >> 20) >= bstar) { unsigned p = atomicAdd(&ccount, 1u); if (p < CAPn) { cu[p] = u.z; cix[p] = bi + 2; } }
                if ((u.w >> 20) >= bstar) { unsigned p = atomicAdd(&ccount, 1u); if (p < CAPn) { cu[p] = u.w; cix[p] = bi + 3; } }
            }
        }
    }
    __syncthreads();
    const int C = (int)min(ccount, (unsigned)CAPn);
    for (int p = t; p < C; p += 256) {
        unsigned up = cu[p]; int ip = cix[p];
        int rank = 0;
        for (int q = 0; q < C; ++q) {
            unsigned uq = cu[q];
            rank += (uq > up) || (uq == up && cix[q] < ip);
        }
        if (rank < BEAMn) { selidx[rank] = ip; selval[rank] = o2f(up); }
    }
    __syncthreads();
    if (t < BEAMn && selidx[t] == tgt) hastgt = 1;
    __syncthreads();
    if (t == 0 && !hastgt) { selidx[BEAMn - 1] = tgt; selval[BEAMn - 1] = rowp[tgt]; }
    __syncthreads();
    if (t < BEAMn) {
        beam_idx[(size_t)row * BEAMn + t] = selidx[t];
        beam_val[(size_t)row * BEAMn + t] = selval[t];
    }
}

// transM[b,k,i,j] = exp2( dot32(E1[beam[b,k,i]], E2[beam[b,k+1,j]]) * LOG2E )
// LINEAR domain (values ~[0.9,1.1]); consumed only by segprod_kernel.
#define TPAD 68
__global__ __launch_bounds__(256) void trans_kernel(const float* __restrict__ E1,
                                                    const float* __restrict__ E2,
                                                    const int* __restrict__ beam_idx,
                                                    float* __restrict__ trans) {
    const int blk = blockIdx.x;           // b*(Sn-1) + k
    const int b = blk / (Sn - 1);
    const int k = blk - b * (Sn - 1);
    const int* bi = beam_idx + ((size_t)(b * Sn + k)) * BEAMn;
    const int* bj = beam_idx + ((size_t)(b * Sn + k + 1)) * BEAMn;
    __shared__ float e1t[RANKn][TPAD];
    __shared__ float e2t[RANKn][TPAD];
    const int t = threadIdx.x;
    {
        const int row = t >> 2, q = t & 3;
        const int rb = q * 8;
        int i1 = bi[row];
        const float4* s1 = (const float4*)(E1 + (size_t)i1 * RANKn) + q * 2;
        float4 a0 = s1[0], a1 = s1[1];
        e1t[rb + 0][row] = a0.x; e1t[rb + 1][row] = a0.y; e1t[rb + 2][row] = a0.z; e1t[rb + 3][row] = a0.w;
        e1t[rb + 4][row] = a1.x; e1t[rb + 5][row] = a1.y; e1t[rb + 6][row] = a1.z; e1t[rb + 7][row] = a1.w;
        int i2 = bj[row];
        const float4* s2 = (const float4*)(E2 + (size_t)i2 * RANKn) + q * 2;
        float4 b0 = s2[0], b1 = s2[1];
        e2t[rb + 0][row] = b0.x; e2t[rb + 1][row] = b0.y; e2t[rb + 2][row] = b0.z; e2t[rb + 3][row] = b0.w;
        e2t[rb + 4][row] = b1.x; e2t[rb + 5][row] = b1.y; e2t[rb + 6][row] = b1.z; e2t[rb + 7][row] = b1.w;
    }
    __syncthreads();
    const int ti = t & 15, tj = t >> 4;
    const int i0 = ti * 4, j0 = tj * 4;
    float acc[4][4] = {};
    #pragma unroll
    for (int r = 0; r < RANKn; ++r) {
        float4 a = *(const float4*)&e1t[r][i0];
        float4 bb = *(const float4*)&e2t[r][j0];
        acc[0][0] += a.x * bb.x; acc[0][1] += a.x * bb.y; acc[0][2] += a.x * bb.z; acc[0][3] += a.x * bb.w;
        acc[1][0] += a.y * bb.x; acc[1][1] += a.y * bb.y; acc[1][2] += a.y * bb.z; acc[1][3] += a.y * bb.w;
        acc[2][0] += a.z * bb.x; acc[2][1] += a.z * bb.y; acc[2][2] += a.z * bb.z; acc[2][3] += a.z * bb.w;
        acc[3][0] += a.w * bb.x; acc[3][1] += a.w * bb.y; acc[3][2] += a.w * bb.z; acc[3][3] += a.w * bb.w;
    }
    float* outp = trans + (size_t)blk * (BEAMn * BEAMn);
    #pragma unroll
    for (int ii = 0; ii < 4; ++ii) {
        float4 o = { EXP2F(acc[ii][0] * LOG2E), EXP2F(acc[ii][1] * LOG2E),
                     EXP2F(acc[ii][2] * LOG2E), EXP2F(acc[ii][3] * LOG2E) };
        *(float4*)&outp[(i0 + ii) * BEAMn + j0] = o;
    }
}

// Segment product: seg s of batch b computes P_s = Prod_{k=16s}^{min(16s+16,255)-1} A_k
// where A_k = mask[k+1] ? M_k * diag(exp(em_{k+1})) : I, all linear-domain f32 with
// per-matmul scalar-max renormalization (log2 offset accumulated in segL).
// Storage convention: segP[seg][j][i] = P_s[i][j]  (transposed), so the finale's
// lane j reads a contiguous 256B row.
__global__ __launch_bounds__(256) void segprod_kernel(const float* __restrict__ trans,
                                                      const float* __restrict__ beam_val,
                                                      const int* __restrict__ mask,
                                                      float* __restrict__ segP,
                                                      float* __restrict__ segL) {
    const int blk = blockIdx.x;           // b*NSEG + s
    const int b = blk >> 4, s = blk & 15;
    const int k0 = s * 16;
    const int nk = min(16, (Sn - 1) - k0);       // 16 (15 for last segment)
    const float* __restrict__ trb = trans + ((size_t)b * (Sn - 1) + k0) * (BEAMn * BEAMn);
    const float* __restrict__ bv  = beam_val + (size_t)b * Sn * BEAMn;
    const int* __restrict__ mk = mask + (size_t)b * Sn;
    __shared__ float Qa[64][64], Qb[64][64], Mld[64][64];
    __shared__ float ev[16][64];
    __shared__ int   mvec[16];
    __shared__ float wmax[4];
    const int t = threadIdx.x;
    const int ti = t & 15, tj = t >> 4;
    const int i0 = ti * 4, j0 = tj * 4;

    for (int x = t; x < 4096; x += 256)
        (&Qa[0][0])[x] = ((x >> 6) == (x & 63)) ? 1.f : 0.f;     // Q = I (== P^T)
    for (int x = t; x < nk * 64; x += 256)
        ev[x >> 6][x & 63] = EXP2F(bv[(size_t)(k0 + (x >> 6) + 1) * BEAMn + (x & 63)] * LOG2E);
    if (t < nk) mvec[t] = mk[k0 + t + 1];
    __syncthreads();

    float (*Qc)[64] = Qa, (*Qn)[64] = Qb;
    float L = 0.f;
    for (int kk = 0; kk < nk; ++kk) {
        // stage A_k = M_k with columns pre-scaled by e (1024 float4s)
        const float4* Ms = (const float4*)(trb + (size_t)kk * (BEAMn * BEAMn));
        #pragma unroll
        for (int q = 0; q < 4; ++q) {
            int p = t + q * 256;                  // float4 index
            int r = p >> 4, cc = (p & 15) * 4;
            float4 v = Ms[p];
            float4 e = *(const float4*)&ev[kk][cc];
            v.x *= e.x; v.y *= e.y; v.z *= e.z; v.w *= e.w;
            *(float4*)&Mld[r][cc] = v;
        }
        __syncthreads();
        const int live = mvec[kk];                // block-uniform
        float acc[4][4];
        if (live) {
            #pragma unroll
            for (int ii = 0; ii < 4; ++ii)
                #pragma unroll
                for (int jj = 0; jj < 4; ++jj) acc[ii][jj] = 0.f;
            for (int r = 0; r < 64; ++r) {
                float4 a  = *(const float4*)&Qc[r][i0];
                float4 bb = *(const float4*)&Mld[r][j0];
                acc[0][0] += a.x * bb.x; acc[0][1] += a.x * bb.y; acc[0][2] += a.x * bb.z; acc[0][3] += a.x * bb.w;
                acc[1][0] += a.y * bb.x; acc[1][1] += a.y * bb.y; acc[1][2] += a.y * bb.z; acc[1][3] += a.y * bb.w;
                acc[2][0] += a.z * bb.x; acc[2][1] += a.z * bb.y; acc[2][2] += a.z * bb.z; acc[2][3] += a.z * bb.w;
                acc[3][0] += a.w * bb.x; acc[3][1] += a.w * bb.y; acc[3][2] += a.w * bb.z; acc[3][3] += a.w * bb.w;
            }
            float lm = acc[0][0];
            #pragma unroll
            for (int ii = 0; ii < 4; ++ii)
                #pragma unroll
                for (int jj = 0; jj < 4; ++jj) lm = fmaxf(lm, acc[ii][jj]);
            for (int off = 32; off; off >>= 1) lm = fmaxf(lm, __shfl_xor(lm, off, 64));
            if ((t & 63) == 0) wmax[t >> 6] = lm;
        }
        __syncthreads();
        if (live) {
            const float m = fmaxf(fmaxf(wmax[0], wmax[1]), fmaxf(wmax[2], wmax[3]));
            const float inv = 1.f / m;
            #pragma unroll
            for (int jj = 0; jj < 4; ++jj) {
                float4 w = { acc[0][jj] * inv, acc[1][jj] * inv, acc[2][jj] * inv, acc[3][jj] * inv };
                *(float4*)&Qn[j0 + jj][i0] = w;   // Qn[j][i] = (P*A)[i][j]
            }
            L += LOG2F(m);
            float (*tmp)[64] = Qc; Qc = Qn; Qn = tmp;
        }
        __syncthreads();
    }
    float* op = segP + (size_t)blk * 4096;
    for (int x = t; x < 4096; x += 256) op[x] = (&Qc[0][0])[x];
    if (t == 0) segL[blk] = L;
}

// Finale: u = exp2(score0), then 16 sequential matvecs u <- u * P_s (with
// register prefetch of the next segment's rows), logsumexp at the end.
__global__ __launch_bounds__(256) void finale_kernel(const float* __restrict__ segP,
                                                     const float* __restrict__ segL,
                                                     const float* __restrict__ beam_val,
                                                     float* __restrict__ out) {
    const int b = blockIdx.x;
    const int t = threadIdx.x;
    const int w = t >> 6, j = t & 63;
    const float* __restrict__ bv = beam_val + (size_t)b * Sn * BEAMn;
    __shared__ float us[BEAMn];
    __shared__ float part[4][BEAMn + 1];
    float sc = bv[j] * LOG2E;                    // log2-domain score0, replicated per wave
    float mx = sc;
    for (int off = 32; off; off >>= 1) mx = fmaxf(mx, __shfl_xor(mx, off, 64));
    float u = EXP2F(sc - mx);
    float Ltot = mx;
    const float* p0 = segP + ((size_t)b * NSEG) * 4096 + (size_t)j * 64 + w * 16;
    float4 ra0 = ((const float4*)p0)[0], ra1 = ((const float4*)p0)[1],
           ra2 = ((const float4*)p0)[2], ra3 = ((const float4*)p0)[3];
    for (int s2 = 0; s2 < NSEG; ++s2) {
        float4 rb0, rb1, rb2, rb3;
        if (s2 + 1 < NSEG) {
            const float* pn = segP + ((size_t)b * NSEG + s2 + 1) * 4096 + (size_t)j * 64 + w * 16;
            rb0 = ((const float4*)pn)[0]; rb1 = ((const float4*)pn)[1];
            rb2 = ((const float4*)pn)[2]; rb3 = ((const float4*)pn)[3];
        }
        if (w == 0) us[j] = u;
        __syncthreads();
        const float4* uu = (const float4*)&us[w * 16];
        float a2 = dot4(ra0, uu[0]) + dot4(ra1, uu[1]) + dot4(ra2, uu[2]) + dot4(ra3, uu[3]);
        part[w][j] = a2;
        __syncthreads();
        float tot = part[0][j] + part[1][j] + part[2][j] + part[3][j];
        float m = tot;
        for (int off = 32; off; off >>= 1) m = fmaxf(m, __shfl_xor(m, off, 64));
        u = tot / m;
        Ltot += LOG2F(m) + segL[b * NSEG + s2];
        ra0 = rb0; ra1 = rb1; ra2 = rb2; ra3 = rb3;
    }
    if (t < BEAMn) {                              // wave 0
        float e = u;
        for (int off = 32; off; off >>= 1) e += __shfl_xor(e, off, 64);
        if (t == 0) atomicAdd(out, -LN2 * (Ltot + LOG2F(e)));
    }
}

// numerator: sum over (b,s) of mask*(em + (s>0)*dot32(E1[tgt_prev],E2[tgt]))
__global__ __launch_bounds__(256) void num_kernel(const float* __restrict__ emis,
                                                  const int* __restrict__ targets,
                                                  const int* __restrict__ mask,
                                                  const float* __restrict__ E1,
                                                  const float* __restrict__ E2,
                                                  float* __restrict__ out) {
    const int gid = blockIdx.x * 256 + threadIdx.x;
    float val = 0.f;
    if (gid < Bn * Sn) {
        int s = gid & (Sn - 1);
        int tg = targets[gid];
        float em = emis[(size_t)gid * Vn + tg];
        float tr = 0.f;
        if (s > 0) {
            int pv = targets[gid - 1];
            const float4* p1 = (const float4*)(E1 + (size_t)pv * RANKn);
            const float4* p2 = (const float4*)(E2 + (size_t)tg * RANKn);
            #pragma unroll
            for (int r = 0; r < 8; ++r) {
                float4 a = p1[r], bb = p2[r];
                tr += a.x * bb.x + a.y * bb.y + a.z * bb.z + a.w * bb.w;
            }
        }
        if (mask[gid]) val = em + tr;
    }
    for (int off = 32; off; off >>= 1) val += __shfl_xor(val, off, 64);
    __shared__ float wsum[4];
    if ((threadIdx.x & 63) == 0) wsum[threadIdx.x >> 6] = val;
    __syncthreads();
    if (threadIdx.x == 0) atomicAdd(out, wsum[0] + wsum[1] + wsum[2] + wsum[3]);
}

extern "C" void kernel_launch(void* const* d_in, const int* in_sizes, int n_in,
                              void* d_out, int out_size, void* d_ws, size_t ws_size,
                              hipStream_t stream) {
    const float* emis    = (const float*)d_in[0];
    const int*   targets = (const int*)d_in[1];
    const int*   mask    = (const int*)d_in[2];   // bool input delivered as int32
    const float* E1      = (const float*)d_in[3];
    const float* E2      = (const float*)d_in[4];
    float* out = (float*)d_out;
    char* ws = (char*)d_ws;
    int*   beam_idx = (int*)ws;                          // 1 MB
    float* beam_val = (float*)(ws + (1 << 20));          // 1 MB
    float* trans    = (float*)(ws + (2 << 20));          // 16*255*4096*4 = 66.8 MB
    float* segP     = (float*)(ws + ((size_t)69 << 20)); // 16*16*4096*4 = 4 MB
    float* segL     = (float*)(ws + ((size_t)74 << 20)); // 1 KB

    (void)hipMemsetAsync(out, 0, sizeof(float), stream);
    hipLaunchKernelGGL(topk_kernel, dim3(Bn * Sn), dim3(256), 0, stream,
                       emis, targets, beam_idx, beam_val);
    hipLaunchKernelGGL(trans_kernel, dim3(Bn * (Sn - 1)), dim3(256), 0, stream,
                       E1, E2, beam_idx, trans);
    hipLaunchKernelGGL(num_kernel, dim3((Bn * Sn + 255) / 256), dim3(256), 0, stream,
                       emis, targets, mask, E1, E2, out);
    hipLaunchKernelGGL(segprod_kernel, dim3(Bn * NSEG), dim3(256), 0, stream,
                       trans, beam_val, mask, segP, segL);
    hipLaunchKernelGGL(finale_kernel, dim3(Bn), dim3(256), 0, stream,
                       segP, segL, beam_val, out);
}